// Round 1
// baseline (1067.348 us; speedup 1.0000x reference)
//
#include <hip/hip_runtime.h>
#include <math.h>

// Problem constants
#define NN 100000
#define EE 1600000
#define FIN 128
#define HCH 128     // H*C for gat1
#define CCH 32      // C
#define NCLONE 19
#define NTYPE 29
#define ETOT (EE + NN)
#define SCAN_B 49   // ceil(NN / 2048)

// ---------------------------------------------------------------- degree + attr sum
__global__ __launch_bounds__(256) void k_deg(const int* __restrict__ ei,
                                             const float* __restrict__ ea,
                                             int* __restrict__ deg,
                                             float* __restrict__ asum) {
    int e = blockIdx.x * 256 + threadIdx.x;
    if (e < EE) {
        int d = ei[EE + e];
        atomicAdd(&deg[d], 1);
        atomicAdd(&asum[d], ea[e]);
    }
}

__global__ __launch_bounds__(256) void k_mean(const int* __restrict__ deg,
                                              const float* __restrict__ asum,
                                              float* __restrict__ mattr) {
    int v = blockIdx.x * 256 + threadIdx.x;
    if (v < NN) mattr[v] = asum[v] / fmaxf((float)deg[v], 1.0f);
}

// ---------------------------------------------------------------- exclusive scan of deg
__global__ __launch_bounds__(256) void k_scan1(const int* __restrict__ deg,
                                               int* __restrict__ offs,
                                               int* __restrict__ bsum) {
    __shared__ int tsum[256];
    int b = blockIdx.x, tid = threadIdx.x;
    int base = b * 2048;
    int loc[8];
    int s = 0;
    #pragma unroll
    for (int i = 0; i < 8; ++i) {
        int idx = base + tid * 8 + i;
        int d = (idx < NN) ? deg[idx] : 0;
        loc[i] = s; s += d;
    }
    tsum[tid] = s;
    __syncthreads();
    for (int off = 1; off < 256; off <<= 1) {
        int v = (tid >= off) ? tsum[tid - off] : 0;
        __syncthreads();
        tsum[tid] += v;
        __syncthreads();
    }
    int texcl = tsum[tid] - s;
    #pragma unroll
    for (int i = 0; i < 8; ++i) {
        int idx = base + tid * 8 + i;
        if (idx < NN) offs[idx] = texcl + loc[i];
    }
    if (tid == 255) bsum[b] = tsum[255];
}

__global__ void k_scan2(int* __restrict__ bsum) {
    if (threadIdx.x == 0) {
        int run = 0;
        for (int i = 0; i < SCAN_B; ++i) { int t = bsum[i]; bsum[i] = run; run += t; }
    }
}

__global__ __launch_bounds__(256) void k_scan3(int* __restrict__ offs,
                                               const int* __restrict__ bsum) {
    int i = blockIdx.x * 256 + threadIdx.x;
    if (i < NN) offs[i] += bsum[i >> 11];
}

// ---------------------------------------------------------------- CSR fill
__global__ __launch_bounds__(256) void k_fill(const int* __restrict__ ei,
                                              const float* __restrict__ ea,
                                              const int* __restrict__ offs,
                                              int* __restrict__ cur,
                                              int* __restrict__ csrc,
                                              float* __restrict__ cea,
                                              int* __restrict__ ceid) {
    int e = blockIdx.x * 256 + threadIdx.x;
    if (e < EE) {
        int d = ei[EE + e];
        int pos = offs[d] + atomicAdd(&cur[d], 1);
        csrc[pos] = ei[e];
        cea[pos] = ea[e];
        ceid[pos] = e;
    }
}

// ---------------------------------------------------------------- GEMM1: x @ [Wl1 | Wr1 | skipW]
// block tile 64 rows x 64 cols, K=128 in two 64-halves. threads 16x16, 4x4 per thread.
__global__ __launch_bounds__(256) void k_gemm1(const float* __restrict__ x,
                                               const float* __restrict__ Wl,
                                               const float* __restrict__ Wr,
                                               const float* __restrict__ Ws,
                                               float* __restrict__ xl,
                                               float* __restrict__ xr,
                                               float* __restrict__ sk) {
    __shared__ float As[64][65];
    __shared__ float Bs[64][64];
    const int tid = threadIdx.x;
    const int row0 = blockIdx.x * 64;
    const int chunk = blockIdx.y;            // 0..5
    const int wsel = chunk >> 1;
    const int c0 = (chunk & 1) * 64;
    const float* W = (wsel == 0) ? Wl : ((wsel == 1) ? Wr : Ws);
    float* out = (wsel == 0) ? xl : ((wsel == 1) ? xr : sk);

    const int tc = tid & 15, tr = tid >> 4;
    float acc[4][4] = {};

    for (int kb = 0; kb < 2; ++kb) {
        // stage A half: 64 rows x 64 k
        for (int i = tid; i < 64 * 64; i += 256) {
            int r = i >> 6, k = i & 63;
            int gr = row0 + r;
            As[r][k] = (gr < NN) ? x[(size_t)gr * FIN + kb * 64 + k] : 0.0f;
        }
        // stage B half
        for (int i = tid; i < 64 * 64; i += 256) {
            int k = i >> 6, c = i & 63;
            Bs[k][c] = W[(kb * 64 + k) * HCH + c0 + c];
        }
        __syncthreads();
        #pragma unroll 8
        for (int kk = 0; kk < 64; ++kk) {
            float4 b4 = *(const float4*)&Bs[kk][tc * 4];
            float a0 = As[tr * 4 + 0][kk];
            float a1 = As[tr * 4 + 1][kk];
            float a2 = As[tr * 4 + 2][kk];
            float a3 = As[tr * 4 + 3][kk];
            acc[0][0] += a0 * b4.x; acc[0][1] += a0 * b4.y; acc[0][2] += a0 * b4.z; acc[0][3] += a0 * b4.w;
            acc[1][0] += a1 * b4.x; acc[1][1] += a1 * b4.y; acc[1][2] += a1 * b4.z; acc[1][3] += a1 * b4.w;
            acc[2][0] += a2 * b4.x; acc[2][1] += a2 * b4.y; acc[2][2] += a2 * b4.z; acc[2][3] += a2 * b4.w;
            acc[3][0] += a3 * b4.x; acc[3][1] += a3 * b4.y; acc[3][2] += a3 * b4.z; acc[3][3] += a3 * b4.w;
        }
        __syncthreads();
    }
    #pragma unroll
    for (int i = 0; i < 4; ++i) {
        int gr = row0 + tr * 4 + i;
        if (gr < NN) {
            float4 v4 = make_float4(acc[i][0], acc[i][1], acc[i][2], acc[i][3]);
            *(float4*)&out[(size_t)gr * HCH + c0 + tc * 4] = v4;
        }
    }
}

// ---------------------------------------------------------------- GAT1 edge pass: one wave per node
__global__ __launch_bounds__(256) void k_gat1(const float* __restrict__ xl1,
                                              const float* __restrict__ xr1,
                                              const float* __restrict__ mattr,
                                              const int* __restrict__ offs,
                                              const int* __restrict__ deg,
                                              const int* __restrict__ csrc,
                                              const float* __restrict__ cea,
                                              const float* __restrict__ att1,
                                              const float* __restrict__ we1,
                                              const float* __restrict__ b1,
                                              const float* __restrict__ skipb,
                                              float* __restrict__ hio) {
    int v = (blockIdx.x * 256 + threadIdx.x) >> 6;
    if (v >= NN) return;
    int l = threadIdx.x & 63;
    int c0 = l * 2;
    float2 xr = *(const float2*)(xr1 + (size_t)v * HCH + c0);
    float2 at = *(const float2*)(att1 + c0);
    float2 we = *(const float2*)(we1 + c0);
    float mr = -INFINITY, den = 0.f, n0 = 0.f, n1 = 0.f;
    int st = offs[v], dg = deg[v];
    for (int i = -1; i < dg; ++i) {
        int s; float eav;
        if (i < 0) { s = v; eav = mattr[v]; }
        else { s = csrc[st + i]; eav = cea[st + i]; }
        float2 xs = *(const float2*)(xl1 + (size_t)s * HCH + c0);
        float m0 = xs.x + xr.x + eav * we.x; m0 = (m0 > 0.f) ? m0 : 0.2f * m0;
        float m1 = xs.y + xr.y + eav * we.y; m1 = (m1 > 0.f) ? m1 : 0.2f * m1;
        float p = m0 * at.x + m1 * at.y;
        p += __shfl_xor(p, 1, 16);
        p += __shfl_xor(p, 2, 16);
        p += __shfl_xor(p, 4, 16);
        p += __shfl_xor(p, 8, 16);
        float nm = fmaxf(mr, p);
        float sc = __expf(mr - nm);
        float ex = __expf(p - nm);
        den = den * sc + ex;
        n0 = n0 * sc + ex * xs.x;
        n1 = n1 * sc + ex * xs.y;
        mr = nm;
    }
    float inv = 1.0f / (den + 1e-16f);
    size_t o = (size_t)v * HCH + c0;
    float2 skv = *(const float2*)(hio + o);   // skip projection pre-stored here
    float2 bb = *(const float2*)(b1 + c0);
    float2 sb = *(const float2*)(skipb + c0);
    float2 res;
    res.x = n0 * inv + bb.x + skv.x + sb.x;
    res.y = n1 * inv + bb.y + skv.y + sb.y;
    *(float2*)(hio + o) = res;
}

// ---------------------------------------------------------------- batchnorm stats
__global__ __launch_bounds__(256) void k_bnstats(const float* __restrict__ h,
                                                 float* __restrict__ bns,
                                                 float* __restrict__ bnq) {
    int tid = blockIdx.x * 256 + threadIdx.x;
    int ch = tid & 127;
    int r0 = tid >> 7;
    int stride = (gridDim.x * 256) >> 7;
    float s = 0.f, q = 0.f;
    for (int r = r0; r < NN; r += stride) {
        float vv = h[(size_t)r * HCH + ch];
        s += vv; q += vv * vv;
    }
    atomicAdd(&bns[ch], s);
    atomicAdd(&bnq[ch], q);
}

__global__ void k_bnfinal(const float* __restrict__ bns, const float* __restrict__ bnq,
                          const float* __restrict__ g, const float* __restrict__ b,
                          float* __restrict__ scale, float* __restrict__ shift) {
    int c = threadIdx.x;
    if (c < 128) {
        float mu = bns[c] * (1.0f / NN);
        float var = bnq[c] * (1.0f / NN) - mu * mu;
        float rs = rsqrtf(var + 1e-5f);
        float a = rs * g[c];
        scale[c] = a;
        shift[c] = b[c] - mu * a;
    }
}

// ---------------------------------------------------------------- GEMM2: elu(bn(h)) @ [Wl2 | Wr2]
__global__ __launch_bounds__(256) void k_gemm2(const float* __restrict__ h,
                                               const float* __restrict__ scale,
                                               const float* __restrict__ shift,
                                               const float* __restrict__ Wl,
                                               const float* __restrict__ Wr,
                                               float* __restrict__ xl2,
                                               float* __restrict__ xr2) {
    __shared__ float As[64][65];
    __shared__ float Bs[64][64];
    const int tid = threadIdx.x;
    const int row0 = blockIdx.x * 64;
    const int tc = tid & 15, tr = tid >> 4;
    float acc[4][4] = {};

    for (int kb = 0; kb < 2; ++kb) {
        for (int i = tid; i < 64 * 64; i += 256) {
            int r = i >> 6, k = i & 63;
            int gr = row0 + r;
            int gk = kb * 64 + k;
            float vv = 0.f;
            if (gr < NN) {
                vv = h[(size_t)gr * HCH + gk] * scale[gk] + shift[gk];
                vv = (vv > 0.f) ? vv : (__expf(vv) - 1.0f);   // elu
            }
            As[r][k] = vv;
        }
        for (int i = tid; i < 64 * 64; i += 256) {
            int k = i >> 6, c = i & 63;
            int gk = kb * 64 + k;
            Bs[k][c] = (c < 32) ? Wl[gk * CCH + c] : Wr[gk * CCH + (c - 32)];
        }
        __syncthreads();
        #pragma unroll 8
        for (int kk = 0; kk < 64; ++kk) {
            float4 b4 = *(const float4*)&Bs[kk][tc * 4];
            float a0 = As[tr * 4 + 0][kk];
            float a1 = As[tr * 4 + 1][kk];
            float a2 = As[tr * 4 + 2][kk];
            float a3 = As[tr * 4 + 3][kk];
            acc[0][0] += a0 * b4.x; acc[0][1] += a0 * b4.y; acc[0][2] += a0 * b4.z; acc[0][3] += a0 * b4.w;
            acc[1][0] += a1 * b4.x; acc[1][1] += a1 * b4.y; acc[1][2] += a1 * b4.z; acc[1][3] += a1 * b4.w;
            acc[2][0] += a2 * b4.x; acc[2][1] += a2 * b4.y; acc[2][2] += a2 * b4.z; acc[2][3] += a2 * b4.w;
            acc[3][0] += a3 * b4.x; acc[3][1] += a3 * b4.y; acc[3][2] += a3 * b4.z; acc[3][3] += a3 * b4.w;
        }
        __syncthreads();
    }
    int cg = tc * 4;
    float* ob = (cg < 32) ? xl2 : xr2;
    int cc = (cg < 32) ? cg : cg - 32;
    #pragma unroll
    for (int i = 0; i < 4; ++i) {
        int gr = row0 + tr * 4 + i;
        if (gr < NN) {
            float4 v4 = make_float4(acc[i][0], acc[i][1], acc[i][2], acc[i][3]);
            *(float4*)&ob[(size_t)gr * CCH + cc] = v4;
        }
    }
}

// ---------------------------------------------------------------- GAT2 edge pass: 32-lane group per node
__global__ __launch_bounds__(256) void k_gat2(const float* __restrict__ xl2,
                                              const float* __restrict__ xr2,
                                              const float* __restrict__ mattr,
                                              const int* __restrict__ offs,
                                              const int* __restrict__ deg,
                                              const int* __restrict__ csrc,
                                              const float* __restrict__ cea,
                                              const int* __restrict__ ceid,
                                              const float* __restrict__ att2,
                                              const float* __restrict__ we2,
                                              const float* __restrict__ b2,
                                              float* __restrict__ h3,
                                              float* __restrict__ wout,
                                              float* __restrict__ Mf,
                                              float* __restrict__ Dn) {
    int v = (blockIdx.x * 256 + threadIdx.x) >> 5;
    if (v >= NN) return;
    int l = threadIdx.x & 31;
    float xr = xr2[(size_t)v * CCH + l];
    float at = att2[l];
    float we = we2[l];
    float mr = -INFINITY, den = 0.f, num = 0.f;
    int st = offs[v], dg = deg[v];
    for (int i = -1; i < dg; ++i) {
        int s, eid; float eav;
        if (i < 0) { s = v; eav = mattr[v]; eid = EE + v; }
        else { int idx = st + i; s = csrc[idx]; eav = cea[idx]; eid = ceid[idx]; }
        float xs = xl2[(size_t)s * CCH + l];
        float m = xs + xr + eav * we;
        m = (m > 0.f) ? m : 0.2f * m;
        float p = m * at;
        p += __shfl_xor(p, 1, 32);
        p += __shfl_xor(p, 2, 32);
        p += __shfl_xor(p, 4, 32);
        p += __shfl_xor(p, 8, 32);
        p += __shfl_xor(p, 16, 32);
        if (l == 0) wout[eid] = p;   // raw alpha, finalized later
        float nm = fmaxf(mr, p);
        float sc = __expf(mr - nm);
        float ex = __expf(p - nm);
        den = den * sc + ex;
        num = num * sc + ex * xs;
        mr = nm;
    }
    if (l == 0) { Mf[v] = mr; Dn[v] = den; }
    float o = num / (den + 1e-16f) + b2[l];
    h3[(size_t)v * CCH + l] = (o > 0.f) ? o : (__expf(o) - 1.0f);   // elu
}

// ---------------------------------------------------------------- finalize attention weights w
__global__ __launch_bounds__(256) void k_wfinal(const int* __restrict__ ei,
                                                const float* __restrict__ Mf,
                                                const float* __restrict__ Dn,
                                                float* __restrict__ wout) {
    int e = blockIdx.x * 256 + threadIdx.x;
    if (e >= ETOT) return;
    int d = (e < EE) ? ei[EE + e] : (e - EE);
    float al = wout[e];
    wout[e] = __expf(al - Mf[d]) / (Dn[d] + 1e-16f);
}

// ---------------------------------------------------------------- heads: fc1 + two log_softmax
__global__ __launch_bounds__(256) void k_head(const float* __restrict__ h3,
                                              const float* __restrict__ fc1W,
                                              const float* __restrict__ fc1b,
                                              const float* __restrict__ Wc,
                                              const float* __restrict__ bc,
                                              const float* __restrict__ Wt,
                                              const float* __restrict__ bt,
                                              float* __restrict__ outp) {
    __shared__ float sW1[32 * 32];
    __shared__ float sWc[32 * NCLONE];
    __shared__ float sWt[32 * NTYPE];
    __shared__ float sb1[32], sbc[NCLONE], sbt[NTYPE];
    int tid = threadIdx.x;
    for (int i = tid; i < 1024; i += 256) sW1[i] = fc1W[i];
    for (int i = tid; i < 32 * NCLONE; i += 256) sWc[i] = Wc[i];
    for (int i = tid; i < 32 * NTYPE; i += 256) sWt[i] = Wt[i];
    if (tid < 32) sb1[tid] = fc1b[tid];
    if (tid < NCLONE) sbc[tid] = bc[tid];
    if (tid < NTYPE) sbt[tid] = bt[tid];
    __syncthreads();
    int g = tid >> 5, l = tid & 31;
    int v = blockIdx.x * 8 + g;
    if (v >= NN) return;
    float x = h3[(size_t)v * CCH + l];
    float acc = sb1[l];
    #pragma unroll
    for (int c = 0; c < 32; ++c) {
        float xc = __shfl(x, c, 32);
        acc += xc * sW1[c * 32 + l];
    }
    float hl = fmaxf(acc, 0.0f);
    float at = (l < NTYPE) ? sbt[l] : 0.0f;
    float ac = (l < NCLONE) ? sbc[l] : 0.0f;
    #pragma unroll
    for (int c = 0; c < 32; ++c) {
        float hc = __shfl(hl, c, 32);
        float wt_ = (l < NTYPE) ? sWt[c * NTYPE + l] : 0.0f;
        float wc_ = (l < NCLONE) ? sWc[c * NCLONE + l] : 0.0f;
        at += hc * wt_;
        ac += hc * wc_;
    }
    // log_softmax over type lanes 0..28
    float vt = (l < NTYPE) ? at : -INFINITY;
    float mt = vt;
    mt = fmaxf(mt, __shfl_xor(mt, 16, 32));
    mt = fmaxf(mt, __shfl_xor(mt, 8, 32));
    mt = fmaxf(mt, __shfl_xor(mt, 4, 32));
    mt = fmaxf(mt, __shfl_xor(mt, 2, 32));
    mt = fmaxf(mt, __shfl_xor(mt, 1, 32));
    float et = __expf(vt - mt);
    float stt = et;
    stt += __shfl_xor(stt, 16, 32);
    stt += __shfl_xor(stt, 8, 32);
    stt += __shfl_xor(stt, 4, 32);
    stt += __shfl_xor(stt, 2, 32);
    stt += __shfl_xor(stt, 1, 32);
    float lt = vt - mt - logf(stt);
    // log_softmax over clone lanes 0..18
    float vc = (l < NCLONE) ? ac : -INFINITY;
    float mc = vc;
    mc = fmaxf(mc, __shfl_xor(mc, 16, 32));
    mc = fmaxf(mc, __shfl_xor(mc, 8, 32));
    mc = fmaxf(mc, __shfl_xor(mc, 4, 32));
    mc = fmaxf(mc, __shfl_xor(mc, 2, 32));
    mc = fmaxf(mc, __shfl_xor(mc, 1, 32));
    float ec = __expf(vc - mc);
    float sc = ec;
    sc += __shfl_xor(sc, 16, 32);
    sc += __shfl_xor(sc, 8, 32);
    sc += __shfl_xor(sc, 4, 32);
    sc += __shfl_xor(sc, 2, 32);
    sc += __shfl_xor(sc, 1, 32);
    float lc = vc - mc - logf(sc);
    size_t ob = (size_t)v * 48;
    if (l < NCLONE) outp[ob + l] = lc;
    if (l < NTYPE) outp[ob + NCLONE + l] = lt;
}

// ---------------------------------------------------------------- launcher
extern "C" void kernel_launch(void* const* d_in, const int* in_sizes, int n_in,
                              void* d_out, int out_size, void* d_ws, size_t ws_size,
                              hipStream_t stream) {
    const float* x     = (const float*)d_in[0];
    const int*   ei    = (const int*)d_in[1];
    const float* ea    = (const float*)d_in[2];
    const float* Wl1   = (const float*)d_in[3];
    const float* Wr1   = (const float*)d_in[4];
    const float* We1   = (const float*)d_in[5];
    const float* att1  = (const float*)d_in[6];
    const float* b1    = (const float*)d_in[7];
    const float* skipW = (const float*)d_in[8];
    const float* skipb = (const float*)d_in[9];
    const float* bng   = (const float*)d_in[10];
    const float* bnb   = (const float*)d_in[11];
    const float* Wl2   = (const float*)d_in[12];
    const float* Wr2   = (const float*)d_in[13];
    const float* We2   = (const float*)d_in[14];
    const float* att2  = (const float*)d_in[15];
    const float* b2    = (const float*)d_in[16];
    const float* fc1W  = (const float*)d_in[17];
    const float* fc1b  = (const float*)d_in[18];
    const float* Wc    = (const float*)d_in[19];
    const float* bc    = (const float*)d_in[20];
    const float* Wt    = (const float*)d_in[21];
    const float* bt    = (const float*)d_in[22];
    float* out = (float*)d_out;
    float* wout = out + (size_t)NN * 48;

    // workspace layout
    float* xl1  = (float*)d_ws;                 // 12.8M floats
    float* xr1  = xl1 + (size_t)NN * HCH;       // 12.8M
    float* hbuf = xr1 + (size_t)NN * HCH;       // 12.8M (skip -> h, in place)
    // region A reuse after gat1:
    float* xl2 = xl1;                           // 3.2M
    float* xr2 = xl1 + (size_t)NN * CCH;        // 3.2M
    float* h3  = xl1 + (size_t)2 * NN * CCH;    // 3.2M
    char* tail = (char*)(hbuf + (size_t)NN * HCH);
    int*   csrc = (int*)tail;
    int*   ceid = csrc + EE;
    float* cea  = (float*)(ceid + EE);
    int*   deg  = (int*)(cea + EE);
    int*   offs = deg + NN;
    int*   cur  = offs + NN;
    float* asum = (float*)(cur + NN);
    float* mattr = asum + NN;
    float* Mf   = mattr + NN;
    float* Dn   = Mf + NN;
    int*   bsum = (int*)(Dn + NN);              // 64
    float* bns  = (float*)(bsum + 64);          // 128
    float* bnq  = bns + 128;                    // 128
    float* scl  = bnq + 128;                    // 128
    float* shf  = scl + 128;                    // 128

    // zero accumulators: deg, offs, cur, asum contiguous (offs is overwritten anyway)
    hipMemsetAsync(deg, 0, (size_t)NN * 4 * sizeof(int), stream);
    hipMemsetAsync(bns, 0, 256 * sizeof(float), stream);

    k_deg<<<(EE + 255) / 256, 256, 0, stream>>>(ei, ea, deg, asum);
    k_mean<<<(NN + 255) / 256, 256, 0, stream>>>(deg, asum, mattr);
    k_scan1<<<SCAN_B, 256, 0, stream>>>(deg, offs, bsum);
    k_scan2<<<1, 64, 0, stream>>>(bsum);
    k_scan3<<<(NN + 255) / 256, 256, 0, stream>>>(offs, bsum);
    k_fill<<<(EE + 255) / 256, 256, 0, stream>>>(ei, ea, offs, cur, csrc, cea, ceid);

    k_gemm1<<<dim3(1563, 6), 256, 0, stream>>>(x, Wl1, Wr1, skipW, xl1, xr1, hbuf);
    k_gat1<<<NN / 4, 256, 0, stream>>>(xl1, xr1, mattr, offs, deg, csrc, cea,
                                       att1, We1, b1, skipb, hbuf);
    k_bnstats<<<512, 256, 0, stream>>>(hbuf, bns, bnq);
    k_bnfinal<<<1, 128, 0, stream>>>(bns, bnq, bng, bnb, scl, shf);
    k_gemm2<<<dim3(1563, 1), 256, 0, stream>>>(hbuf, scl, shf, Wl2, Wr2, xl2, xr2);
    k_gat2<<<NN / 8, 256, 0, stream>>>(xl2, xr2, mattr, offs, deg, csrc, cea, ceid,
                                       att2, We2, b2, h3, wout, Mf, Dn);
    k_wfinal<<<(ETOT + 255) / 256, 256, 0, stream>>>(ei, Mf, Dn, wout);
    k_head<<<NN / 8, 256, 0, stream>>>(h3, fc1W, fc1b, Wc, bc, Wt, bt, out);
}